// Round 3
// baseline (2181.406 us; speedup 1.0000x reference)
//
#include <hip/hip_runtime.h>
#include <math.h>

#define MTOK 16384
#define NEXP 256
#define KDIM 7168

#define BM 128
#define BN 64
#define BK 16
#define LDA 132   // BM + 4 pad
#define LDB 68    // BN + 4 pad

#define CAP 4096          // max rescored tokens (expect ~500)
#define TAU 2e-5f         // margin threshold, ~40 sigma of f32 GEMM noise

// ================= K1: f32 GEMM + sigmoid =================
__launch_bounds__(256)
__global__ void gemm_f32_k(const float* __restrict__ X,
                           const float* __restrict__ W,
                           float* __restrict__ S) {
    __shared__ float As[BK][LDA];
    __shared__ float Bs[BK][LDB];
    const int tid = threadIdx.x;
    const int m0 = blockIdx.x * BM;
    const int n0 = blockIdx.y * BN;

    const int lr = tid >> 2;
    const int lc = tid & 3;
    const int tn = tid & 15;
    const int tm = tid >> 4;

    const float* xg = X + (size_t)m0 * KDIM + lc * 4;
    const float* wg = W + (size_t)n0 * KDIM + lc * 4;

    float acc[8][4];
#pragma unroll
    for (int i = 0; i < 8; ++i)
#pragma unroll
        for (int j = 0; j < 4; ++j) acc[i][j] = 0.f;

    for (int k0 = 0; k0 < KDIM; k0 += BK) {
        float4 a0 = *(const float4*)(xg + (size_t)lr * KDIM + k0);
        float4 a1 = *(const float4*)(xg + (size_t)(lr + 64) * KDIM + k0);
        float4 b0 = *(const float4*)(wg + (size_t)lr * KDIM + k0);
        __syncthreads();
        As[lc * 4 + 0][lr] = a0.x;      As[lc * 4 + 1][lr] = a0.y;
        As[lc * 4 + 2][lr] = a0.z;      As[lc * 4 + 3][lr] = a0.w;
        As[lc * 4 + 0][lr + 64] = a1.x; As[lc * 4 + 1][lr + 64] = a1.y;
        As[lc * 4 + 2][lr + 64] = a1.z; As[lc * 4 + 3][lr + 64] = a1.w;
        Bs[lc * 4 + 0][lr] = b0.x;      Bs[lc * 4 + 1][lr] = b0.y;
        Bs[lc * 4 + 2][lr] = b0.z;      Bs[lc * 4 + 3][lr] = b0.w;
        __syncthreads();
#pragma unroll
        for (int k = 0; k < BK; ++k) {
            float4 av0 = *(const float4*)&As[k][tm * 8];
            float4 av1 = *(const float4*)&As[k][tm * 8 + 4];
            float4 bv  = *(const float4*)&Bs[k][tn * 4];
            float a[8] = {av0.x, av0.y, av0.z, av0.w, av1.x, av1.y, av1.z, av1.w};
            float b[4] = {bv.x, bv.y, bv.z, bv.w};
#pragma unroll
            for (int i = 0; i < 8; ++i)
#pragma unroll
                for (int j = 0; j < 4; ++j)
                    acc[i][j] = fmaf(a[i], b[j], acc[i][j]);
        }
    }

#pragma unroll
    for (int i = 0; i < 8; ++i) {
        const int row = m0 + tm * 8 + i;
        float4 o;
        o.x = 1.f / (1.f + expf(-acc[i][0]));
        o.y = 1.f / (1.f + expf(-acc[i][1]));
        o.z = 1.f / (1.f + expf(-acc[i][2]));
        o.w = 1.f / (1.f + expf(-acc[i][3]));
        *(float4*)(S + (size_t)row * NEXP + n0 + tn * 4) = o;
    }
}

// ================= K2: f32 routing + margin flagging =================
__launch_bounds__(256)
__global__ void route_flag_k(const float* __restrict__ S,
                             const float* __restrict__ bias,
                             float* __restrict__ out,
                             int* __restrict__ list,
                             int* __restrict__ count) {
    __shared__ float sraw[4][256];
    const int wv   = threadIdx.x >> 6;
    const int lane = threadIdx.x & 63;
    const int token = blockIdx.x * 4 + wv;
    const float NINF = -__builtin_inff();
    const float PINF =  __builtin_inff();

    const float* row = S + (size_t)token * NEXP;
    float4 v = *(const float4*)(row + lane * 4);
    *(float4*)&sraw[wv][lane * 4] = v;

    const int e0 = lane * 4;
    float4 bi4 = *(const float4*)(bias + e0);
    float b0 = v.x + bi4.x;
    float b1 = v.y + bi4.y;
    float b2 = v.z + bi4.z;
    float b3 = v.w + bi4.w;

    bool flag = false;

    // per-lane top-3 of 4
    float m1 = b0, m2 = NINF, m3 = NINF;
    {
        float x;
        x = b1; if (x > m1) { m3 = m2; m2 = m1; m1 = x; } else if (x > m2) { m3 = m2; m2 = x; } else if (x > m3) m3 = x;
        x = b2; if (x > m1) { m3 = m2; m2 = m1; m1 = x; } else if (x > m2) { m3 = m2; m2 = x; } else if (x > m3) m3 = x;
        x = b3; if (x > m1) { m3 = m2; m2 = m1; m1 = x; } else if (x > m2) { m3 = m2; m2 = x; } else if (x > m3) m3 = x;
    }
    // merge top-3 triples across the 8 lanes of this group
#pragma unroll
    for (int w = 1; w <= 4; w <<= 1) {
        float o1 = __shfl_xor(m1, w);
        float o2 = __shfl_xor(m2, w);
        float o3 = __shfl_xor(m3, w);
        float n1  = fmaxf(m1, o1);
        float lo1 = fminf(m1, o1);
        float hi2 = fmaxf(m2, o2);
        float n2  = fmaxf(lo1, hi2);
        float n3  = fmaxf(fminf(lo1, hi2), fmaxf(m3, o3));
        m1 = n1; m2 = n2; m3 = n3;
    }
    const float gs = m1 + m2;
    flag |= (m2 - m3) < TAU;        // within-group top-2 membership margin

    const int g = lane >> 3;
    int rank = 0;
#pragma unroll
    for (int j = 0; j < 8; ++j) {
        float gj = __shfl(gs, j * 8);
        rank += (gj > gs) || (gj == gs && j < g);
    }
    const bool sel = rank < 4;

    // group-selection margin: min(selected gs) - max(unselected gs)
    {
        float a = sel ? gs : PINF;
        float b = sel ? NINF : gs;
#pragma unroll
        for (int w = 1; w < 64; w <<= 1) {
            a = fminf(a, __shfl_xor(a, w));
            b = fmaxf(b, __shfl_xor(b, w));
        }
        flag |= (a - b) < TAU;
    }

    if (!sel) { b0 = NINF; b1 = NINF; b2 = NINF; b3 = NINF; }

    // stable top-8 (+1 extra iteration for the rank8-vs-rank9 margin)
    int myidx = 0;
    float prev = 0.f;
#pragma unroll
    for (int it = 0; it < 9; ++it) {
        float bv = b0; int bi = e0;
        if (b1 > bv) { bv = b1; bi = e0 + 1; }
        if (b2 > bv) { bv = b2; bi = e0 + 2; }
        if (b3 > bv) { bv = b3; bi = e0 + 3; }
#pragma unroll
        for (int w = 1; w < 64; w <<= 1) {
            float ov = __shfl_xor(bv, w);
            int   oi = __shfl_xor(bi, w);
            if (ov > bv || (ov == bv && oi < bi)) { bv = ov; bi = oi; }
        }
        if (it > 0) flag |= (prev - bv) < TAU;   // consecutive winner gap
        prev = bv;
        if (it < 8) {
            if (lane == it) myidx = bi;
            if ((bi >> 2) == lane) {
                switch (bi & 3) {
                    case 0: b0 = NINF; break;
                    case 1: b1 = NINF; break;
                    case 2: b2 = NINF; break;
                    case 3: b3 = NINF; break;
                }
            }
        }
    }

    const bool anyflag = __any((int)flag);

    __syncthreads();

    float wval = (lane < 8) ? sraw[wv][myidx] : 0.f;
    float s = wval;
    s += __shfl_xor(s, 1);
    s += __shfl_xor(s, 2);
    s += __shfl_xor(s, 4);
    if (lane < 8) {
        float wout = wval / (s + 1e-20f) * 2.5f;
        out[(size_t)token * 8 + lane] = wout;
        out[(size_t)MTOK * 8 + (size_t)token * 8 + lane] = (float)myidx;
    }

    if (anyflag && lane == 0) {
        int f = atomicAdd(count, 1);
        if (f < CAP) list[f] = token;
    }
}

// ================= K3: f64 GEMM over flagged (gathered) rows =================
__launch_bounds__(256)
__global__ void gemm_f64_flag_k(const float* __restrict__ X,
                                const float* __restrict__ W,
                                const int* __restrict__ list,
                                const int* __restrict__ count,
                                double* __restrict__ Ld) {
    const int cnt = min(*count, CAP);
    const int m0 = blockIdx.x * BM;
    if (m0 >= cnt) return;

    __shared__ float As[BK][LDA];
    __shared__ float Bs[BK][LDB];
    const int tid = threadIdx.x;
    const int n0 = blockIdx.y * BN;

    const int lr = tid >> 2;
    const int lc = tid & 3;
    const int tn = tid & 15;
    const int tm = tid >> 4;

    const int gi_lo = list[min(m0 + lr, cnt - 1)];
    const int gi_hi = list[min(m0 + lr + 64, cnt - 1)];
    const float* xg_lo = X + (size_t)gi_lo * KDIM + lc * 4;
    const float* xg_hi = X + (size_t)gi_hi * KDIM + lc * 4;
    const float* wg = W + (size_t)n0 * KDIM + lc * 4;

    double acc[8][4];
#pragma unroll
    for (int i = 0; i < 8; ++i)
#pragma unroll
        for (int j = 0; j < 4; ++j) acc[i][j] = 0.0;

    for (int k0 = 0; k0 < KDIM; k0 += BK) {
        float4 a0 = *(const float4*)(xg_lo + k0);
        float4 a1 = *(const float4*)(xg_hi + k0);
        float4 b0 = *(const float4*)(wg + (size_t)lr * KDIM + k0);
        __syncthreads();
        As[lc * 4 + 0][lr] = a0.x;      As[lc * 4 + 1][lr] = a0.y;
        As[lc * 4 + 2][lr] = a0.z;      As[lc * 4 + 3][lr] = a0.w;
        As[lc * 4 + 0][lr + 64] = a1.x; As[lc * 4 + 1][lr + 64] = a1.y;
        As[lc * 4 + 2][lr + 64] = a1.z; As[lc * 4 + 3][lr + 64] = a1.w;
        Bs[lc * 4 + 0][lr] = b0.x;      Bs[lc * 4 + 1][lr] = b0.y;
        Bs[lc * 4 + 2][lr] = b0.z;      Bs[lc * 4 + 3][lr] = b0.w;
        __syncthreads();
#pragma unroll
        for (int k = 0; k < BK; ++k) {
            float4 av0 = *(const float4*)&As[k][tm * 8];
            float4 av1 = *(const float4*)&As[k][tm * 8 + 4];
            float4 bv  = *(const float4*)&Bs[k][tn * 4];
            double ad[8] = {(double)av0.x, (double)av0.y, (double)av0.z, (double)av0.w,
                            (double)av1.x, (double)av1.y, (double)av1.z, (double)av1.w};
            double bd[4] = {(double)bv.x, (double)bv.y, (double)bv.z, (double)bv.w};
#pragma unroll
            for (int i = 0; i < 8; ++i)
#pragma unroll
                for (int j = 0; j < 4; ++j)
                    acc[i][j] = fma(ad[i], bd[j], acc[i][j]);
        }
    }

#pragma unroll
    for (int i = 0; i < 8; ++i) {
        const int r = m0 + tm * 8 + i;
        if (r < cnt) {
            double4 o;
            o.x = acc[i][0]; o.y = acc[i][1]; o.z = acc[i][2]; o.w = acc[i][3];
            *(double4*)(Ld + (size_t)r * NEXP + n0 + tn * 4) = o;
        }
    }
}

// ================= K4: exact f64 routing for flagged tokens =================
// one wave per flagged token (block = 64 threads)
__launch_bounds__(64)
__global__ void route_exact_k(const double* __restrict__ Ld,
                              const float* __restrict__ bias,
                              const int* __restrict__ list,
                              const int* __restrict__ count,
                              float* __restrict__ out) {
    const int cnt = min(*count, CAP);
    const int f = blockIdx.x;
    if (f >= cnt) return;
    const int lane = threadIdx.x;
    const int token = list[f];
    const double NINF = -__builtin_inf();

    const double* row = Ld + (size_t)f * NEXP;
    const int e0 = lane * 4;
    double4 l4 = *(const double4*)(row + e0);

    double s0 = 1.0 / (1.0 + exp(-l4.x));
    double s1 = 1.0 / (1.0 + exp(-l4.y));
    double s2 = 1.0 / (1.0 + exp(-l4.z));
    double s3 = 1.0 / (1.0 + exp(-l4.w));

    float4 bi4 = *(const float4*)(bias + e0);
    double b0 = s0 + (double)bi4.x;
    double b1 = s1 + (double)bi4.y;
    double b2 = s2 + (double)bi4.z;
    double b3 = s3 + (double)bi4.w;

    double m1 = b0, m2 = NINF;
    if (b1 > m1) { m2 = m1; m1 = b1; } else if (b1 > m2) m2 = b1;
    if (b2 > m1) { m2 = m1; m1 = b2; } else if (b2 > m2) m2 = b2;
    if (b3 > m1) { m2 = m1; m1 = b3; } else if (b3 > m2) m2 = b3;
#pragma unroll
    for (int w = 1; w <= 4; w <<= 1) {
        double o1 = __shfl_xor(m1, w);
        double o2 = __shfl_xor(m2, w);
        double nm1 = fmax(m1, o1);
        double nm2 = fmax(fmin(m1, o1), fmax(m2, o2));
        m1 = nm1; m2 = nm2;
    }
    const double gs = m1 + m2;
    const int g = lane >> 3;

    int rank = 0;
#pragma unroll
    for (int j = 0; j < 8; ++j) {
        double gj = __shfl(gs, j * 8);
        rank += (gj > gs) || (gj == gs && j < g);
    }
    if (rank >= 4) { b0 = NINF; b1 = NINF; b2 = NINF; b3 = NINF; }

    int myidx = 0;
#pragma unroll
    for (int it = 0; it < 8; ++it) {
        double bv = b0; int bi = e0;
        if (b1 > bv) { bv = b1; bi = e0 + 1; }
        if (b2 > bv) { bv = b2; bi = e0 + 2; }
        if (b3 > bv) { bv = b3; bi = e0 + 3; }
#pragma unroll
        for (int w = 1; w < 64; w <<= 1) {
            double ov = __shfl_xor(bv, w);
            int    oi = __shfl_xor(bi, w);
            if (ov > bv || (ov == bv && oi < bi)) { bv = ov; bi = oi; }
        }
        if (lane == it) myidx = bi;
        if ((bi >> 2) == lane) {
            switch (bi & 3) {
                case 0: b0 = NINF; break;
                case 1: b1 = NINF; break;
                case 2: b2 = NINF; break;
                case 3: b3 = NINF; break;
            }
        }
    }

    // gather raw score of myidx via shuffles (no LDS, single wave)
    double g0 = __shfl(s0, myidx >> 2);
    double g1 = __shfl(s1, myidx >> 2);
    double g2 = __shfl(s2, myidx >> 2);
    double g3 = __shfl(s3, myidx >> 2);
    const int ss = myidx & 3;
    double wval = (lane < 8) ? (ss == 0 ? g0 : ss == 1 ? g1 : ss == 2 ? g2 : g3) : 0.0;
    double s = wval;
    s += __shfl_xor(s, 1);
    s += __shfl_xor(s, 2);
    s += __shfl_xor(s, 4);
    if (lane < 8) {
        float wout = (float)(wval / (s + 1e-20) * 2.5);
        out[(size_t)token * 8 + lane] = wout;
        out[(size_t)MTOK * 8 + (size_t)token * 8 + lane] = (float)myidx;
    }
}

__global__ void init_k(int* count) { *count = 0; }

extern "C" void kernel_launch(void* const* d_in, const int* in_sizes, int n_in,
                              void* d_out, int out_size, void* d_ws, size_t ws_size,
                              hipStream_t stream) {
    const float* X    = (const float*)d_in[0];
    const float* W    = (const float*)d_in[1];
    const float* bias = (const float*)d_in[2];
    float* out = (float*)d_out;

    // ws layout
    float*  Lf   = (float*)d_ws;                                   // 16,777,216 B
    int*    list = (int*)((char*)d_ws + 16777216);                 // CAP*4 = 16 KB
    int*    cnt  = (int*)((char*)d_ws + 16777216 + CAP * 4);       // 4 B
    double* Ld   = (double*)((char*)d_ws + 16777216 + CAP * 4 + 256); // 8,388,608 B

    init_k<<<1, 1, 0, stream>>>(cnt);

    dim3 g1(MTOK / BM, NEXP / BN);
    gemm_f32_k<<<g1, 256, 0, stream>>>(X, W, Lf);

    route_flag_k<<<MTOK / 4, 256, 0, stream>>>(Lf, bias, out, list, cnt);

    dim3 g3(CAP / BM, NEXP / BN);
    gemm_f64_flag_k<<<g3, 256, 0, stream>>>(X, W, list, cnt, Ld);

    route_exact_k<<<CAP, 64, 0, stream>>>(Ld, bias, list, cnt, out);
}

// Round 4
// 454.934 us; speedup vs baseline: 4.7950x; 4.7950x over previous
//
#include <hip/hip_runtime.h>
#include <math.h>

#define MTOK 16384
#define NEXP 256
#define KDIM 7168

#define CAPR 1024         // max rescored tokens (expect ~200-500)
#define KSPLIT 8
#define KCH (KDIM / KSPLIT)   // 896
#define TAU 2e-5f         // proven margin threshold (round-3 passed with this)

typedef _Float16 f16;
typedef __attribute__((ext_vector_type(8))) f16 f16x8;
typedef __attribute__((ext_vector_type(4))) f16 f16x4;
typedef __attribute__((ext_vector_type(4))) float f32x4;

// ================= K1: fp16x2-split MFMA GEMM + sigmoid =================
// S[m][e] = sigmoid(x[m,:] . W[e,:]) ; logit = aa + (a_x b_w + b_x a_w)/2048
#define BM 64
#define BN 128
#define BK 64
#define LDH 72   // fp16 elements per LDS row (64 + 8 pad) -> 144B stride, 16B aligned

__launch_bounds__(256, 2)
__global__ void gemm_fp16x2_k(const float* __restrict__ X,
                              const float* __restrict__ W,
                              float* __restrict__ S) {
    __shared__ f16 Ahi[BM][LDH];
    __shared__ f16 Alo[BM][LDH];
    __shared__ f16 Bhi[BN][LDH];
    __shared__ f16 Blo[BN][LDH];

    const int tid  = threadIdx.x;
    const int lane = tid & 63;
    const int wid  = tid >> 6;
    const int wr   = wid >> 1;      // 0..1 -> row half (32 rows)
    const int wc   = wid & 1;       // 0..1 -> col half (64 cols)
    const int m0 = blockIdx.x * BM;
    const int n0 = blockIdx.y * BN;

    // staging maps
    const int arow = tid >> 2;      // 0..63
    const int ac   = tid & 3;       // chunk base, chunks ac + i*4 (i=0..3)
    const int brow = tid >> 1;      // 0..127
    const int bc   = tid & 1;       // chunks bc + i*2 (i=0..7)

    const float* xg = X + (size_t)(m0 + arow) * KDIM;
    const float* wg = W + (size_t)(n0 + brow) * KDIM;

    f32x4 accA[2][4];
    f32x4 accB[2][4];
#pragma unroll
    for (int i = 0; i < 2; ++i)
#pragma unroll
        for (int j = 0; j < 4; ++j) { accA[i][j] = (f32x4)0.f; accB[i][j] = (f32x4)0.f; }

    const int mr = wr * 32;
    const int nc = wc * 64;
    const int fr = lane & 15;       // fragment row (within 16)
    const int fq = lane >> 4;       // 0..3

    for (int k0 = 0; k0 < KDIM; k0 += BK) {
        float4 av[4], bv[8];
#pragma unroll
        for (int i = 0; i < 4; ++i)
            av[i] = *(const float4*)(xg + k0 + (ac + i * 4) * 4);
#pragma unroll
        for (int i = 0; i < 8; ++i)
            bv[i] = *(const float4*)(wg + k0 + (bc + i * 2) * 4);

        __syncthreads();   // previous iteration's fragment reads done

#pragma unroll
        for (int i = 0; i < 4; ++i) {
            const int ke = (ac + i * 4) * 4;
            f16x4 h, l;
            h.x = (f16)av[i].x; l.x = (f16)((av[i].x - (float)h.x) * 2048.f);
            h.y = (f16)av[i].y; l.y = (f16)((av[i].y - (float)h.y) * 2048.f);
            h.z = (f16)av[i].z; l.z = (f16)((av[i].z - (float)h.z) * 2048.f);
            h.w = (f16)av[i].w; l.w = (f16)((av[i].w - (float)h.w) * 2048.f);
            *(f16x4*)&Ahi[arow][ke] = h;
            *(f16x4*)&Alo[arow][ke] = l;
        }
#pragma unroll
        for (int i = 0; i < 8; ++i) {
            const int ke = (bc + i * 2) * 4;
            f16x4 h, l;
            h.x = (f16)bv[i].x; l.x = (f16)((bv[i].x - (float)h.x) * 2048.f);
            h.y = (f16)bv[i].y; l.y = (f16)((bv[i].y - (float)h.y) * 2048.f);
            h.z = (f16)bv[i].z; l.z = (f16)((bv[i].z - (float)h.z) * 2048.f);
            h.w = (f16)bv[i].w; l.w = (f16)((bv[i].w - (float)h.w) * 2048.f);
            *(f16x4*)&Bhi[brow][ke] = h;
            *(f16x4*)&Blo[brow][ke] = l;
        }

        __syncthreads();

#pragma unroll
        for (int ks = 0; ks < 2; ++ks) {
            const int ke = ks * 32 + fq * 8;   // fp16 element offset within row
            f16x8 ah[2], al[2], bh[4], bl[4];
#pragma unroll
            for (int mi = 0; mi < 2; ++mi) {
                ah[mi] = *(const f16x8*)&Ahi[mr + mi * 16 + fr][ke];
                al[mi] = *(const f16x8*)&Alo[mr + mi * 16 + fr][ke];
            }
#pragma unroll
            for (int ni = 0; ni < 4; ++ni) {
                bh[ni] = *(const f16x8*)&Bhi[nc + ni * 16 + fr][ke];
                bl[ni] = *(const f16x8*)&Blo[nc + ni * 16 + fr][ke];
            }
#pragma unroll
            for (int mi = 0; mi < 2; ++mi)
#pragma unroll
                for (int ni = 0; ni < 4; ++ni) {
                    accA[mi][ni] = __builtin_amdgcn_mfma_f32_16x16x32_f16(ah[mi], bh[ni], accA[mi][ni], 0, 0, 0);
                    accB[mi][ni] = __builtin_amdgcn_mfma_f32_16x16x32_f16(ah[mi], bl[ni], accB[mi][ni], 0, 0, 0);
                    accB[mi][ni] = __builtin_amdgcn_mfma_f32_16x16x32_f16(al[mi], bh[ni], accB[mi][ni], 0, 0, 0);
                }
        }
    }

    // epilogue: combine, sigmoid, store. C layout: row=(lane>>4)*4+r, col=lane&15
#pragma unroll
    for (int mi = 0; mi < 2; ++mi)
#pragma unroll
        for (int ni = 0; ni < 4; ++ni) {
            const int e = n0 + nc + ni * 16 + fr;
#pragma unroll
            for (int r = 0; r < 4; ++r) {
                const int m = m0 + mr + mi * 16 + fq * 4 + r;
                float logit = accA[mi][ni][r] + accB[mi][ni][r] * (1.f / 2048.f);
                S[(size_t)m * NEXP + e] = 1.f / (1.f + expf(-logit));
            }
        }
}

// ================= K2: f32 routing + margin flagging =================
__launch_bounds__(256)
__global__ void route_flag_k(const float* __restrict__ S,
                             const float* __restrict__ bias,
                             float* __restrict__ out,
                             int* __restrict__ list,
                             int* __restrict__ count) {
    __shared__ float sraw[4][256];
    const int wv   = threadIdx.x >> 6;
    const int lane = threadIdx.x & 63;
    const int token = blockIdx.x * 4 + wv;
    const float NINF = -__builtin_inff();
    const float PINF =  __builtin_inff();

    const float* row = S + (size_t)token * NEXP;
    float4 v = *(const float4*)(row + lane * 4);
    *(float4*)&sraw[wv][lane * 4] = v;

    const int e0 = lane * 4;
    float4 bi4 = *(const float4*)(bias + e0);
    float b0 = v.x + bi4.x;
    float b1 = v.y + bi4.y;
    float b2 = v.z + bi4.z;
    float b3 = v.w + bi4.w;

    bool flag = false;

    // per-lane top-2 of 4
    float m1 = b0, m2 = NINF;
    if (b1 > m1) { m2 = m1; m1 = b1; } else if (b1 > m2) m2 = b1;
    if (b2 > m1) { m2 = m1; m1 = b2; } else if (b2 > m2) m2 = b2;
    if (b3 > m1) { m2 = m1; m1 = b3; } else if (b3 > m2) m2 = b3;
#pragma unroll
    for (int w = 1; w <= 4; w <<= 1) {
        float o1 = __shfl_xor(m1, w);
        float o2 = __shfl_xor(m2, w);
        float nm1 = fmaxf(m1, o1);
        float nm2 = fmaxf(fminf(m1, o1), fmaxf(m2, o2));
        m1 = nm1; m2 = nm2;
    }
    const float gs = m1 + m2;
    const int g = lane >> 3;

    int rank = 0;
#pragma unroll
    for (int j = 0; j < 8; ++j) {
        float gj = __shfl(gs, j * 8);
        rank += (gj > gs) || (gj == gs && j < g);
    }
    const bool sel = rank < 4;

    // group-selection margin (2*TAU: covers within-group top-2 perturbation too)
    {
        float a = sel ? gs : PINF;
        float b = sel ? NINF : gs;
#pragma unroll
        for (int w = 1; w < 64; w <<= 1) {
            a = fminf(a, __shfl_xor(a, w));
            b = fmaxf(b, __shfl_xor(b, w));
        }
        flag |= (a - b) < 2.f * TAU;
    }

    if (!sel) { b0 = NINF; b1 = NINF; b2 = NINF; b3 = NINF; }

    // stable top-8 (+1 iteration for rank8-vs-rank9 margin)
    int myidx = 0;
    float prev = 0.f;
#pragma unroll
    for (int it = 0; it < 9; ++it) {
        float bv = b0; int bi = e0;
        if (b1 > bv) { bv = b1; bi = e0 + 1; }
        if (b2 > bv) { bv = b2; bi = e0 + 2; }
        if (b3 > bv) { bv = b3; bi = e0 + 3; }
#pragma unroll
        for (int w = 1; w < 64; w <<= 1) {
            float ov = __shfl_xor(bv, w);
            int   oi = __shfl_xor(bi, w);
            if (ov > bv || (ov == bv && oi < bi)) { bv = ov; bi = oi; }
        }
        if (it > 0) flag |= (prev - bv) < TAU;
        prev = bv;
        if (it < 8) {
            if (lane == it) myidx = bi;
            if ((bi >> 2) == lane) {
                switch (bi & 3) {
                    case 0: b0 = NINF; break;
                    case 1: b1 = NINF; break;
                    case 2: b2 = NINF; break;
                    case 3: b3 = NINF; break;
                }
            }
        }
    }

    const bool anyflag = __any((int)flag);

    __syncthreads();

    float wval = (lane < 8) ? sraw[wv][myidx] : 0.f;
    float s = wval;
    s += __shfl_xor(s, 1);
    s += __shfl_xor(s, 2);
    s += __shfl_xor(s, 4);
    if (lane < 8) {
        float wout = wval / (s + 1e-20f) * 2.5f;
        out[(size_t)token * 8 + lane] = wout;
        out[(size_t)MTOK * 8 + (size_t)token * 8 + lane] = (float)myidx;
    }

    if (anyflag && lane == 0) {
        int f = atomicAdd(count, 1);
        if (f < CAPR) list[f] = token;
    }
}

// ================= K3: K-split f64 partial GEMM over flagged rows =================
// grid (CAPR/64, NEXP/64, KSPLIT); Ldp[s][r][e] partial over k in [s*KCH,(s+1)*KCH)
__launch_bounds__(256)
__global__ void rescore_k(const float* __restrict__ X,
                          const float* __restrict__ W,
                          const int* __restrict__ list,
                          const int* __restrict__ count,
                          double* __restrict__ Ldp) {
    const int cnt = min(*count, CAPR);
    const int m0 = blockIdx.x * 64;
    if (m0 >= cnt) return;
    const int n0 = blockIdx.y * 64;
    const int ks = blockIdx.z;
    const int kbase = ks * KCH;

    __shared__ float As[16][66];
    __shared__ float Bs[16][66];
    const int tid = threadIdx.x;
    const int row = tid >> 2;       // 0..63
    const int c   = tid & 3;        // float4 chunk
    const int tm  = tid >> 4;       // 0..15
    const int tn  = tid & 15;       // 0..15

    const int gi = list[min(m0 + row, cnt - 1)];
    const float* xg = X + (size_t)gi * KDIM + c * 4;
    const float* wg = W + (size_t)(n0 + row) * KDIM + c * 4;

    double acc[4][4];
#pragma unroll
    for (int i = 0; i < 4; ++i)
#pragma unroll
        for (int j = 0; j < 4; ++j) acc[i][j] = 0.0;

    for (int k0 = kbase; k0 < kbase + KCH; k0 += 16) {
        float4 a = *(const float4*)(xg + k0);
        float4 b = *(const float4*)(wg + k0);
        __syncthreads();
        As[c * 4 + 0][row] = a.x; As[c * 4 + 1][row] = a.y;
        As[c * 4 + 2][row] = a.z; As[c * 4 + 3][row] = a.w;
        Bs[c * 4 + 0][row] = b.x; Bs[c * 4 + 1][row] = b.y;
        Bs[c * 4 + 2][row] = b.z; Bs[c * 4 + 3][row] = b.w;
        __syncthreads();
#pragma unroll
        for (int k = 0; k < 16; ++k) {
            double ad[4], bd[4];
#pragma unroll
            for (int i = 0; i < 4; ++i) ad[i] = (double)As[k][tm * 4 + i];
#pragma unroll
            for (int j = 0; j < 4; ++j) bd[j] = (double)Bs[k][tn * 4 + j];
#pragma unroll
            for (int i = 0; i < 4; ++i)
#pragma unroll
                for (int j = 0; j < 4; ++j)
                    acc[i][j] = fma(ad[i], bd[j], acc[i][j]);
        }
    }

#pragma unroll
    for (int i = 0; i < 4; ++i) {
        const int r = m0 + tm * 4 + i;
        if (r < cnt) {
#pragma unroll
            for (int j = 0; j < 4; ++j)
                Ldp[((size_t)ks * CAPR + r) * NEXP + n0 + tn * 4 + j] = acc[i][j];
        }
    }
}

// ================= K4: exact f64 routing for flagged tokens =================
__launch_bounds__(64)
__global__ void route_exact_k(const double* __restrict__ Ldp,
                              const float* __restrict__ bias,
                              const int* __restrict__ list,
                              const int* __restrict__ count,
                              float* __restrict__ out) {
    const int cnt = min(*count, CAPR);
    const int f = blockIdx.x;
    if (f >= cnt) return;
    const int lane = threadIdx.x;
    const int token = list[f];
    const double NINF = -__builtin_inf();

    const int e0 = lane * 4;
    double l0 = 0.0, l1 = 0.0, l2 = 0.0, l3 = 0.0;
#pragma unroll
    for (int s = 0; s < KSPLIT; ++s) {      // fixed order -> deterministic
        double4 p = *(const double4*)(Ldp + ((size_t)s * CAPR + f) * NEXP + e0);
        l0 += p.x; l1 += p.y; l2 += p.z; l3 += p.w;
    }

    double s0 = 1.0 / (1.0 + exp(-l0));
    double s1 = 1.0 / (1.0 + exp(-l1));
    double s2 = 1.0 / (1.0 + exp(-l2));
    double s3 = 1.0 / (1.0 + exp(-l3));

    float4 bi4 = *(const float4*)(bias + e0);
    double b0 = s0 + (double)bi4.x;
    double b1 = s1 + (double)bi4.y;
    double b2 = s2 + (double)bi4.z;
    double b3 = s3 + (double)bi4.w;

    double m1 = b0, m2 = NINF;
    if (b1 > m1) { m2 = m1; m1 = b1; } else if (b1 > m2) m2 = b1;
    if (b2 > m1) { m2 = m1; m1 = b2; } else if (b2 > m2) m2 = b2;
    if (b3 > m1) { m2 = m1; m1 = b3; } else if (b3 > m2) m2 = b3;
#pragma unroll
    for (int w = 1; w <= 4; w <<= 1) {
        double o1 = __shfl_xor(m1, w);
        double o2 = __shfl_xor(m2, w);
        double nm1 = fmax(m1, o1);
        double nm2 = fmax(fmin(m1, o1), fmax(m2, o2));
        m1 = nm1; m2 = nm2;
    }
    const double gs = m1 + m2;
    const int g = lane >> 3;

    int rank = 0;
#pragma unroll
    for (int j = 0; j < 8; ++j) {
        double gj = __shfl(gs, j * 8);
        rank += (gj > gs) || (gj == gs && j < g);
    }
    if (rank >= 4) { b0 = NINF; b1 = NINF; b2 = NINF; b3 = NINF; }

    int myidx = 0;
#pragma unroll
    for (int it = 0; it < 8; ++it) {
        double bv = b0; int bi = e0;
        if (b1 > bv) { bv = b1; bi = e0 + 1; }
        if (b2 > bv) { bv = b2; bi = e0 + 2; }
        if (b3 > bv) { bv = b3; bi = e0 + 3; }
#pragma unroll
        for (int w = 1; w < 64; w <<= 1) {
            double ov = __shfl_xor(bv, w);
            int    oi = __shfl_xor(bi, w);
            if (ov > bv || (ov == bv && oi < bi)) { bv = ov; bi = oi; }
        }
        if (lane == it) myidx = bi;
        if ((bi >> 2) == lane) {
            switch (bi & 3) {
                case 0: b0 = NINF; break;
                case 1: b1 = NINF; break;
                case 2: b2 = NINF; break;
                case 3: b3 = NINF; break;
            }
        }
    }

    double g0 = __shfl(s0, myidx >> 2);
    double g1 = __shfl(s1, myidx >> 2);
    double g2 = __shfl(s2, myidx >> 2);
    double g3 = __shfl(s3, myidx >> 2);
    const int ss = myidx & 3;
    double wval = (lane < 8) ? (ss == 0 ? g0 : ss == 1 ? g1 : ss == 2 ? g2 : g3) : 0.0;
    double s = wval;
    s += __shfl_xor(s, 1);
    s += __shfl_xor(s, 2);
    s += __shfl_xor(s, 4);
    if (lane < 8) {
        float wout = (float)(wval / (s + 1e-20) * 2.5);
        out[(size_t)token * 8 + lane] = wout;
        out[(size_t)MTOK * 8 + (size_t)token * 8 + lane] = (float)myidx;
    }
}

__global__ void init_k(int* count) { *count = 0; }

extern "C" void kernel_launch(void* const* d_in, const int* in_sizes, int n_in,
                              void* d_out, int out_size, void* d_ws, size_t ws_size,
                              hipStream_t stream) {
    const float* X    = (const float*)d_in[0];
    const float* W    = (const float*)d_in[1];
    const float* bias = (const float*)d_in[2];
    float* out = (float*)d_out;

    // ws layout: [Lf f32 16.8MB -- aliased later by Ldp f64 16.8MB][list][cnt]
    // Alias is safe: Lf dead after route_flag; rescore writes Ldp afterwards.
    float*  Lf   = (float*)d_ws;
    double* Ldp  = (double*)d_ws;                       // KSPLIT*CAPR*NEXP*8 = 16.8MB
    int*    list = (int*)((char*)d_ws + 16777216);      // CAPR*4 = 4KB
    int*    cnt  = (int*)((char*)d_ws + 16777216 + CAPR * 4);

    init_k<<<1, 1, 0, stream>>>(cnt);

    dim3 g1(MTOK / BM, NEXP / BN);                      // 256 x 2
    gemm_fp16x2_k<<<g1, 256, 0, stream>>>(X, W, Lf);

    route_flag_k<<<MTOK / 4, 256, 0, stream>>>(Lf, bias, out, list, cnt);

    dim3 g3(CAPR / 64, NEXP / 64, KSPLIT);              // 16 x 4 x 8
    rescore_k<<<g3, 256, 0, stream>>>(X, W, list, cnt, Ldp);

    route_exact_k<<<CAPR, 64, 0, stream>>>(Ldp, bias, list, cnt, out);
}